// Round 16
// baseline (86.480 us; speedup 1.0000x reference)
//
#include <hip/hip_runtime.h>

#define T_ 500
#define R_ 50
#define NS_ 1000
#define H1_ 32
#define H2_ 16
#define NEG_ 0.2f
#define NROWS_ (NS_ * R_)   // 50000

__device__ __forceinline__ float lrelu(float x) { return x >= 0.f ? x : NEG_ * x; }

__device__ __forceinline__ float wave_sum_dpp(float x) {
    int t;
    t = __builtin_amdgcn_update_dpp(0, __float_as_int(x), 0x111, 0xf, 0xf, true);
    x += __int_as_float(t);
    t = __builtin_amdgcn_update_dpp(0, __float_as_int(x), 0x112, 0xf, 0xf, true);
    x += __int_as_float(t);
    t = __builtin_amdgcn_update_dpp(0, __float_as_int(x), 0x114, 0xf, 0xf, true);
    x += __int_as_float(t);
    t = __builtin_amdgcn_update_dpp(0, __float_as_int(x), 0x118, 0xf, 0xf, true);
    x += __int_as_float(t);
    t = __builtin_amdgcn_update_dpp(0, __float_as_int(x), 0x142, 0xf, 0xf, true);
    x += __int_as_float(t);
    t = __builtin_amdgcn_update_dpp(0, __float_as_int(x), 0x143, 0xf, 0xf, true);
    x += __int_as_float(t);
    return __int_as_float(__builtin_amdgcn_readlane(__float_as_int(x), 63));
}

// ---------------- logits chain (unchanged from best run R12) ----------------
__global__ __launch_bounds__(256) void k1_xw(const float* __restrict__ state,
                                             const float* __restrict__ payoff,
                                             const float* __restrict__ noise,
                                             const float* __restrict__ w,
                                             float* __restrict__ y1) {
    __shared__ float xs[504];
    __shared__ float red[8][H1_];
    int t = blockIdx.x, tid = threadIdx.x;
    for (int u = tid; u < T_; u += 256) xs[2 + u] = payoff[t * T_ + u];
    if (tid == 0) {
        xs[0] = state[t * 2];     xs[1] = state[t * 2 + 1];
        xs[502] = noise[t * 2];   xs[503] = noise[t * 2 + 1];
    }
    __syncthreads();
    int c = tid & 31, kg = tid >> 5;
    float acc = 0.f;
#pragma unroll 7
    for (int f = kg; f < 504; f += 8) acc += xs[f] * w[f * H1_ + c];
    red[kg][c] = acc;
    __syncthreads();
    if (tid < H1_) {
        float a = 0.f;
#pragma unroll
        for (int s = 0; s < 8; ++s) a += red[s][tid];
        y1[t * H1_ + tid] = a;
    }
}

__global__ __launch_bounds__(256) void k2_adj_fused(const float* __restrict__ adj,
                                                    const float* __restrict__ y1,
                                                    const float* __restrict__ b,
                                                    const float* __restrict__ gamma,
                                                    const float* __restrict__ beta,
                                                    const float* __restrict__ w2,
                                                    float* __restrict__ y2) {
    __shared__ float arow[T_];
    __shared__ float red[8][H1_];
    __shared__ float h1row[H1_];
    int t = blockIdx.x, tid = threadIdx.x;
    for (int u = tid; u < T_; u += 256) arow[u] = adj[t * T_ + u];
    __syncthreads();
    int c = tid & 31, kg = tid >> 5;
    float acc = 0.f;
#pragma unroll 4
    for (int u = kg; u < T_; u += 8) acc += arow[u] * y1[u * H1_ + c];
    red[kg][c] = acc;
    __syncthreads();
    if (tid < H1_) {
        float a = 0.f;
#pragma unroll
        for (int s = 0; s < 8; ++s) a += red[s][tid];
        h1row[tid] = lrelu((a + b[tid]) * gamma[t] + beta[t]);
    }
    __syncthreads();
    if (tid < H2_) {
        float a = 0.f;
#pragma unroll
        for (int cc = 0; cc < H1_; ++cc) a += h1row[cc] * w2[cc * H2_ + tid];
        y2[t * H2_ + tid] = a;
    }
}

__global__ __launch_bounds__(256) void k3_adj2_aw(const float* __restrict__ adj,
                                                  const float* __restrict__ y2,
                                                  const float* __restrict__ b2,
                                                  const float* __restrict__ gamma,
                                                  const float* __restrict__ beta,
                                                  const float* __restrict__ aw,
                                                  float* __restrict__ part1) {
    __shared__ float arow[T_];
    __shared__ float red[16][H2_];
    __shared__ float xfr[H2_];
    int t = blockIdx.x, tid = threadIdx.x;
    for (int u = tid; u < T_; u += 256) arow[u] = adj[t * T_ + u];
    __syncthreads();
    int c2 = tid & 15, kg = tid >> 4;
    float acc = 0.f;
#pragma unroll 4
    for (int u = kg; u < T_; u += 16) acc += arow[u] * y2[u * H2_ + c2];
    red[kg][c2] = acc;
    __syncthreads();
    if (tid < H2_) {
        float a = 0.f;
#pragma unroll
        for (int s = 0; s < 16; ++s) a += red[s][tid];
        xfr[tid] = lrelu((a + b2[tid]) * gamma[t] + beta[t]);
    }
    __syncthreads();
    float acc0 = 0.f, acc1 = 0.f;
#pragma unroll
    for (int c = 0; c < H2_; ++c) {
        float xv = xfr[c];
        const float* awr = aw + (t * H2_ + c) * T_;
        acc0 += xv * awr[tid];
        if (tid < T_ - 256) acc1 += xv * awr[256 + tid];
    }
    part1[t * T_ + tid] = acc0;
    if (tid < T_ - 256) part1[t * T_ + 256 + tid] = acc1;
}

__global__ __launch_bounds__(256) void k4_logits_part(const float* __restrict__ dloc,
                                                      const float* __restrict__ av,
                                                      const float* __restrict__ part1,
                                                      float* __restrict__ part2) {
    int r = blockIdx.x;
    int jb = blockIdx.y & 1, q = blockIdx.y >> 1;
    __shared__ float drow[125];
    int tid = threadIdx.x;
    int t0 = q * 125;
    if (tid < 125) drow[tid] = dloc[r * T_ + t0 + tid];
    __syncthreads();
    if (tid >= 250) return;
    int j = jb * 250 + tid;
    float acc = 0.f;
#pragma unroll 5
    for (int i = 0; i < 125; ++i) {
        int t = t0 + i;
        acc += drow[i] * av[t * T_ + j] + part1[t * T_ + j];
    }
    part2[q * (R_ * T_) + r * T_ + j] = acc;
}

__global__ __launch_bounds__(256) void k4_reduce_exp(const float* __restrict__ part2,
                                                     float* __restrict__ elog) {
    int gid = blockIdx.x * 256 + threadIdx.x;
    if (gid >= R_ * T_) return;
    float v = part2[gid] + part2[R_ * T_ + gid] +
              part2[2 * R_ * T_ + gid] + part2[3 * R_ * T_ + gid];
    elog[gid] = __expf(v);
}

// ---- Pass A: per-row sums only (reduce lives here; writes 4 B/row) ----
__global__ __launch_bounds__(256) void k7a_sums(const float4* __restrict__ gu,
                                                const float4* __restrict__ elog,
                                                float* __restrict__ invsum) {
    int wave = threadIdx.x >> 6, lane = threadIdx.x & 63;
    int row = blockIdx.x * 4 + wave;
    int r = row % R_;
    const float4* grow = gu + (size_t)row * 125;
    const float4* erow = elog + r * 125;
    bool has1 = lane < 61;

    float4 g0 = grow[lane];
    float4 e0 = erow[lane];
    float4 g1, e1;
    if (has1) { g1 = grow[64 + lane]; e1 = erow[64 + lane]; }

    float p0 = e0.x * __builtin_amdgcn_rcpf(-__log2f(g0.x));
    float p1 = e0.y * __builtin_amdgcn_rcpf(-__log2f(g0.y));
    float p2 = e0.z * __builtin_amdgcn_rcpf(-__log2f(g0.z));
    float p3 = e0.w * __builtin_amdgcn_rcpf(-__log2f(g0.w));
    float p4 = 0.f, p5 = 0.f, p6 = 0.f, p7 = 0.f;
    if (has1) {
        p4 = e1.x * __builtin_amdgcn_rcpf(-__log2f(g1.x));
        p5 = e1.y * __builtin_amdgcn_rcpf(-__log2f(g1.y));
        p6 = e1.z * __builtin_amdgcn_rcpf(-__log2f(g1.z));
        p7 = e1.w * __builtin_amdgcn_rcpf(-__log2f(g1.w));
    }
    float s = ((p0 + p1) + (p2 + p3)) + ((p4 + p5) + (p6 + p7));
    float tot = wave_sum_dpp(s);
    if (lane == 0) invsum[row] = __builtin_amdgcn_rcpf(tot);
}

// ---- Pass B: pure elementwise stream — NO reduction barrier between loads
// and stores. out = elog * rcp(-log2 gu) * invsum[row]. ----
__global__ __launch_bounds__(256) void k7b_norm(const float4* __restrict__ gu,
                                                const float4* __restrict__ elog,
                                                const float* __restrict__ invsum,
                                                float4* __restrict__ out) {
    int wave = threadIdx.x >> 6, lane = threadIdx.x & 63;
    int row = blockIdx.x * 4 + wave;
    int r = row % R_;
    bool has1 = lane < 61;

    float inv = invsum[row];                 // uniform-address broadcast (L2)
    const float4* grow = gu + (size_t)row * 125;
    const float4* erow = elog + r * 125;
    float4 g0 = grow[lane];
    float4 e0 = erow[lane];
    float4 g1, e1;
    if (has1) { g1 = grow[64 + lane]; e1 = erow[64 + lane]; }

    float4* orow = out + (size_t)row * 125;
    float4 o0;
    o0.x = e0.x * __builtin_amdgcn_rcpf(-__log2f(g0.x)) * inv;
    o0.y = e0.y * __builtin_amdgcn_rcpf(-__log2f(g0.y)) * inv;
    o0.z = e0.z * __builtin_amdgcn_rcpf(-__log2f(g0.z)) * inv;
    o0.w = e0.w * __builtin_amdgcn_rcpf(-__log2f(g0.w)) * inv;
    orow[lane] = o0;
    if (has1) {
        float4 o1;
        o1.x = e1.x * __builtin_amdgcn_rcpf(-__log2f(g1.x)) * inv;
        o1.y = e1.y * __builtin_amdgcn_rcpf(-__log2f(g1.y)) * inv;
        o1.z = e1.z * __builtin_amdgcn_rcpf(-__log2f(g1.z)) * inv;
        o1.w = e1.w * __builtin_amdgcn_rcpf(-__log2f(g1.w)) * inv;
        orow[64 + lane] = o1;
    }
}

extern "C" void kernel_launch(void* const* d_in, const int* in_sizes, int n_in,
                              void* d_out, int out_size, void* d_ws, size_t ws_size,
                              hipStream_t stream) {
    const float* state  = (const float*)d_in[0];
    const float* dloc   = (const float*)d_in[1];
    const float* noise  = (const float*)d_in[2];
    const float* gu     = (const float*)d_in[3];
    const float* payoff = (const float*)d_in[4];
    const float* adj    = (const float*)d_in[5];
    const float* g1w    = (const float*)d_in[6];
    const float* g1b    = (const float*)d_in[7];
    const float* g2w    = (const float*)d_in[8];
    const float* g2b    = (const float*)d_in[9];
    const float* gamma  = (const float*)d_in[10];
    const float* beta   = (const float*)d_in[11];
    const float* aw     = (const float*)d_in[12];
    const float* av     = (const float*)d_in[13];
    float* out = (float*)d_out;

    float* ws     = (float*)d_ws;
    float* y1     = ws;           // 16000
    float* y2     = ws + 16000;   // 8000
    float* part1  = ws + 24000;   // 250000
    float* part2  = ws + 274000;  // 100000
    float* elog   = ws + 374000;  // 25000
    float* invsum = ws + 400000;  // 50000  (total 450000 floats = 1.8 MB)

    k1_xw<<<T_, 256, 0, stream>>>(state, payoff, noise, g1w, y1);
    k2_adj_fused<<<T_, 256, 0, stream>>>(adj, y1, g1b, gamma, beta, g2w, y2);
    k3_adj2_aw<<<T_, 256, 0, stream>>>(adj, y2, g2b, gamma, beta, aw, part1);
    k4_logits_part<<<dim3(R_, 8), 256, 0, stream>>>(dloc, av, part1, part2);
    k4_reduce_exp<<<(R_ * T_ + 255) / 256, 256, 0, stream>>>(part2, elog);
    k7a_sums<<<NROWS_ / 4, 256, 0, stream>>>(
        (const float4*)gu, (const float4*)elog, invsum);
    k7b_norm<<<NROWS_ / 4, 256, 0, stream>>>(
        (const float4*)gu, (const float4*)elog, invsum, (float4*)out);
}

// Round 17
// 71.872 us; speedup vs baseline: 1.2033x; 1.2033x over previous
//
#include <hip/hip_runtime.h>

#define T_ 500
#define R_ 50
#define NS_ 1000
#define H1_ 32
#define H2_ 16
#define NEG_ 0.2f
#define NROWS_ (NS_ * R_)   // 50000

__device__ __forceinline__ float lrelu(float x) { return x >= 0.f ? x : NEG_ * x; }

__device__ __forceinline__ float wave_sum_dpp(float x) {
    int t;
    t = __builtin_amdgcn_update_dpp(0, __float_as_int(x), 0x111, 0xf, 0xf, true);
    x += __int_as_float(t);
    t = __builtin_amdgcn_update_dpp(0, __float_as_int(x), 0x112, 0xf, 0xf, true);
    x += __int_as_float(t);
    t = __builtin_amdgcn_update_dpp(0, __float_as_int(x), 0x114, 0xf, 0xf, true);
    x += __int_as_float(t);
    t = __builtin_amdgcn_update_dpp(0, __float_as_int(x), 0x118, 0xf, 0xf, true);
    x += __int_as_float(t);
    t = __builtin_amdgcn_update_dpp(0, __float_as_int(x), 0x142, 0xf, 0xf, true);
    x += __int_as_float(t);
    t = __builtin_amdgcn_update_dpp(0, __float_as_int(x), 0x143, 0xf, 0xf, true);
    x += __int_as_float(t);
    return __int_as_float(__builtin_amdgcn_readlane(__float_as_int(x), 63));
}

// ---------------- logits chain (R12-best, unchanged) ----------------
__global__ __launch_bounds__(256) void k1_xw(const float* __restrict__ state,
                                             const float* __restrict__ payoff,
                                             const float* __restrict__ noise,
                                             const float* __restrict__ w,
                                             float* __restrict__ y1) {
    __shared__ float xs[504];
    __shared__ float red[8][H1_];
    int t = blockIdx.x, tid = threadIdx.x;
    for (int u = tid; u < T_; u += 256) xs[2 + u] = payoff[t * T_ + u];
    if (tid == 0) {
        xs[0] = state[t * 2];     xs[1] = state[t * 2 + 1];
        xs[502] = noise[t * 2];   xs[503] = noise[t * 2 + 1];
    }
    __syncthreads();
    int c = tid & 31, kg = tid >> 5;
    float acc = 0.f;
#pragma unroll 7
    for (int f = kg; f < 504; f += 8) acc += xs[f] * w[f * H1_ + c];
    red[kg][c] = acc;
    __syncthreads();
    if (tid < H1_) {
        float a = 0.f;
#pragma unroll
        for (int s = 0; s < 8; ++s) a += red[s][tid];
        y1[t * H1_ + tid] = a;
    }
}

__global__ __launch_bounds__(256) void k2_adj_fused(const float* __restrict__ adj,
                                                    const float* __restrict__ y1,
                                                    const float* __restrict__ b,
                                                    const float* __restrict__ gamma,
                                                    const float* __restrict__ beta,
                                                    const float* __restrict__ w2,
                                                    float* __restrict__ y2) {
    __shared__ float arow[T_];
    __shared__ float red[8][H1_];
    __shared__ float h1row[H1_];
    int t = blockIdx.x, tid = threadIdx.x;
    for (int u = tid; u < T_; u += 256) arow[u] = adj[t * T_ + u];
    __syncthreads();
    int c = tid & 31, kg = tid >> 5;
    float acc = 0.f;
#pragma unroll 4
    for (int u = kg; u < T_; u += 8) acc += arow[u] * y1[u * H1_ + c];
    red[kg][c] = acc;
    __syncthreads();
    if (tid < H1_) {
        float a = 0.f;
#pragma unroll
        for (int s = 0; s < 8; ++s) a += red[s][tid];
        h1row[tid] = lrelu((a + b[tid]) * gamma[t] + beta[t]);
    }
    __syncthreads();
    if (tid < H2_) {
        float a = 0.f;
#pragma unroll
        for (int cc = 0; cc < H1_; ++cc) a += h1row[cc] * w2[cc * H2_ + tid];
        y2[t * H2_ + tid] = a;
    }
}

__global__ __launch_bounds__(256) void k3_adj2_aw(const float* __restrict__ adj,
                                                  const float* __restrict__ y2,
                                                  const float* __restrict__ b2,
                                                  const float* __restrict__ gamma,
                                                  const float* __restrict__ beta,
                                                  const float* __restrict__ aw,
                                                  float* __restrict__ part1) {
    __shared__ float arow[T_];
    __shared__ float red[16][H2_];
    __shared__ float xfr[H2_];
    int t = blockIdx.x, tid = threadIdx.x;
    for (int u = tid; u < T_; u += 256) arow[u] = adj[t * T_ + u];
    __syncthreads();
    int c2 = tid & 15, kg = tid >> 4;
    float acc = 0.f;
#pragma unroll 4
    for (int u = kg; u < T_; u += 16) acc += arow[u] * y2[u * H2_ + c2];
    red[kg][c2] = acc;
    __syncthreads();
    if (tid < H2_) {
        float a = 0.f;
#pragma unroll
        for (int s = 0; s < 16; ++s) a += red[s][tid];
        xfr[tid] = lrelu((a + b2[tid]) * gamma[t] + beta[t]);
    }
    __syncthreads();
    float acc0 = 0.f, acc1 = 0.f;
#pragma unroll
    for (int c = 0; c < H2_; ++c) {
        float xv = xfr[c];
        const float* awr = aw + (t * H2_ + c) * T_;
        acc0 += xv * awr[tid];
        if (tid < T_ - 256) acc1 += xv * awr[256 + tid];
    }
    part1[t * T_ + tid] = acc0;
    if (tid < T_ - 256) part1[t * T_ + 256 + tid] = acc1;
}

__global__ __launch_bounds__(256) void k4_logits_part(const float* __restrict__ dloc,
                                                      const float* __restrict__ av,
                                                      const float* __restrict__ part1,
                                                      float* __restrict__ part2) {
    int r = blockIdx.x;
    int jb = blockIdx.y & 1, q = blockIdx.y >> 1;
    __shared__ float drow[125];
    int tid = threadIdx.x;
    int t0 = q * 125;
    if (tid < 125) drow[tid] = dloc[r * T_ + t0 + tid];
    __syncthreads();
    if (tid >= 250) return;
    int j = jb * 250 + tid;
    float acc = 0.f;
#pragma unroll 5
    for (int i = 0; i < 125; ++i) {
        int t = t0 + i;
        acc += drow[i] * av[t * T_ + j] + part1[t * T_ + j];
    }
    part2[q * (R_ * T_) + r * T_ + j] = acc;
}

__global__ __launch_bounds__(256) void k4_reduce_exp(const float* __restrict__ part2,
                                                     float* __restrict__ elog) {
    int gid = blockIdx.x * 256 + threadIdx.x;
    if (gid >= R_ * T_) return;
    float v = part2[gid] + part2[R_ * T_ + gid] +
              part2[2 * R_ * T_ + gid] + part2[3 * R_ * T_ + gid];
    elog[gid] = __expf(v);
}

// One wave per row (R12 code), but 512-thread blocks: 8 waves/block, 6250
// blocks — halves the block dispatch/teardown rate needed to keep CUs full.
__global__ __launch_bounds__(512) void k7_softmax(const float4* __restrict__ gu,
                                                  const float4* __restrict__ elog,
                                                  float4* __restrict__ out) {
    int wave = threadIdx.x >> 6;
    int lane = threadIdx.x & 63;
    int row = blockIdx.x * 8 + wave;  // < 50000
    int r = row % R_;
    const float4* grow = gu + (size_t)row * 125;
    const float4* erow = elog + r * 125;
    bool has1 = lane < 61;

    float4 g0 = grow[lane];
    float4 e0 = erow[lane];
    float4 g1, e1;
    if (has1) {
        g1 = grow[64 + lane];
        e1 = erow[64 + lane];
    }
    float p[8];
    p[0] = e0.x * __builtin_amdgcn_rcpf(-__log2f(g0.x));
    p[1] = e0.y * __builtin_amdgcn_rcpf(-__log2f(g0.y));
    p[2] = e0.z * __builtin_amdgcn_rcpf(-__log2f(g0.z));
    p[3] = e0.w * __builtin_amdgcn_rcpf(-__log2f(g0.w));
    if (has1) {
        p[4] = e1.x * __builtin_amdgcn_rcpf(-__log2f(g1.x));
        p[5] = e1.y * __builtin_amdgcn_rcpf(-__log2f(g1.y));
        p[6] = e1.z * __builtin_amdgcn_rcpf(-__log2f(g1.z));
        p[7] = e1.w * __builtin_amdgcn_rcpf(-__log2f(g1.w));
    } else {
        p[4] = p[5] = p[6] = p[7] = 0.f;
    }
    float s = ((p[0] + p[1]) + (p[2] + p[3])) + ((p[4] + p[5]) + (p[6] + p[7]));
    float tot = wave_sum_dpp(s);
    float inv = __builtin_amdgcn_rcpf(tot);

    float4* orow = out + (size_t)row * 125;
    float4 o0 = {p[0] * inv, p[1] * inv, p[2] * inv, p[3] * inv};
    orow[lane] = o0;
    if (has1) {
        float4 o1 = {p[4] * inv, p[5] * inv, p[6] * inv, p[7] * inv};
        orow[64 + lane] = o1;
    }
}

extern "C" void kernel_launch(void* const* d_in, const int* in_sizes, int n_in,
                              void* d_out, int out_size, void* d_ws, size_t ws_size,
                              hipStream_t stream) {
    const float* state  = (const float*)d_in[0];
    const float* dloc   = (const float*)d_in[1];
    const float* noise  = (const float*)d_in[2];
    const float* gu     = (const float*)d_in[3];
    const float* payoff = (const float*)d_in[4];
    const float* adj    = (const float*)d_in[5];
    const float* g1w    = (const float*)d_in[6];
    const float* g1b    = (const float*)d_in[7];
    const float* g2w    = (const float*)d_in[8];
    const float* g2b    = (const float*)d_in[9];
    const float* gamma  = (const float*)d_in[10];
    const float* beta   = (const float*)d_in[11];
    const float* aw     = (const float*)d_in[12];
    const float* av     = (const float*)d_in[13];
    float* out = (float*)d_out;

    float* ws     = (float*)d_ws;
    float* y1     = ws;           // 16000
    float* y2     = ws + 16000;   // 8000
    float* part1  = ws + 24000;   // 250000
    float* part2  = ws + 274000;  // 100000
    float* elog   = ws + 374000;  // 25000

    k1_xw<<<T_, 256, 0, stream>>>(state, payoff, noise, g1w, y1);
    k2_adj_fused<<<T_, 256, 0, stream>>>(adj, y1, g1b, gamma, beta, g2w, y2);
    k3_adj2_aw<<<T_, 256, 0, stream>>>(adj, y2, g2b, gamma, beta, aw, part1);
    k4_logits_part<<<dim3(R_, 8), 256, 0, stream>>>(dloc, av, part1, part2);
    k4_reduce_exp<<<(R_ * T_ + 255) / 256, 256, 0, stream>>>(part2, elog);
    k7_softmax<<<NROWS_ / 8, 512, 0, stream>>>(
        (const float4*)gu, (const float4*)elog, (float4*)out);
}